// Round 1
// baseline (595.128 us; speedup 1.0000x reference)
//
#include <hip/hip_runtime.h>
#include <math.h>

#define BB 64
#define NN 1000
#define CC 64
#define TT 32

// ---------------- Pass 1a: A[b,t,c] = sum_n X[b,n,c,t] * U1[n] ----------------
// grid: BB * (CC/8) blocks, 256 threads. thread = (t = tid&31, c = cblk*8 + tid>>5)
__global__ __launch_bounds__(256) void k_A(const float* __restrict__ X,
                                           const float* __restrict__ U1,
                                           float* __restrict__ A) {
    int b    = blockIdx.x / (CC / 8);
    int cblk = blockIdx.x % (CC / 8);
    int t = threadIdx.x & 31;
    int c = cblk * 8 + (threadIdx.x >> 5);
    const float* xp = X + (size_t)b * NN * CC * TT + (size_t)c * TT + t;
    float acc = 0.f;
#pragma unroll 4
    for (int n = 0; n < NN; ++n) {
        acc += U1[n] * xp[(size_t)n * CC * TT];
    }
    A[((size_t)b * TT + t) * CC + c] = acc;
}

// ---------------- Pass 1b: rhs[b,n,t] = sum_c X[b,n,c,t] * U3[c] ----------------
// one thread per (b,n,t). idx = ((b*NN)+n)*TT + t
__global__ __launch_bounds__(256) void k_rhs(const float* __restrict__ X,
                                             const float* __restrict__ U3,
                                             float* __restrict__ rhs) {
    size_t idx = (size_t)blockIdx.x * blockDim.x + threadIdx.x;
    int t = (int)(idx & 31);
    size_t bn = idx >> 5;  // b*NN + n
    const float* xp = X + bn * (CC * TT) + t;
    float acc = 0.f;
#pragma unroll 8
    for (int c = 0; c < CC; ++c) {
        acc += U3[c] * xp[c * TT];
    }
    rhs[idx] = acc;
}

// ---------------- G[b,c,s] = sum_n U2[c,n] * rhs[b,n,s] ----------------
// one thread per (b,c,s): idx = ((b*CC)+c)*TT + s
__global__ __launch_bounds__(256) void k_G(const float* __restrict__ rhs,
                                           const float* __restrict__ U2,
                                           float* __restrict__ G) {
    size_t idx = (size_t)blockIdx.x * blockDim.x + threadIdx.x;
    int s = (int)(idx & 31);
    int c = (int)((idx >> 5) & (CC - 1));
    int b = (int)(idx >> 11);
    const float* rp = rhs + (size_t)b * NN * TT + s;
    const float* up = U2 + (size_t)c * NN;
    float acc = 0.f;
#pragma unroll 4
    for (int n = 0; n < NN; ++n) {
        acc += up[n] * rp[(size_t)n * TT];
    }
    G[idx] = acc;
}

// ---------------- E[b,t,u]: scores -> sigmoid -> Ve @ . -> softmax over t ------
// one block per b, 1024 threads = (t = tid>>5, u = tid&31)
__global__ __launch_bounds__(1024) void k_E(const float* __restrict__ A,
                                            const float* __restrict__ G,
                                            const float* __restrict__ be,
                                            const float* __restrict__ Ve,
                                            float* __restrict__ E) {
    int b = blockIdx.x;
    int u = threadIdx.x & 31;
    int t = threadIdx.x >> 5;
    __shared__ float sig[TT][TT];
    __shared__ float e0[TT][TT];

    const float* Ab = A + ((size_t)b * TT + t) * CC;
    const float* Gb = G + (size_t)b * CC * TT;
    float sc = be[t * TT + u];
#pragma unroll
    for (int c = 0; c < CC; ++c) {
        sc += Ab[c] * Gb[c * TT + u];
    }
    sig[t][u] = 1.f / (1.f + __expf(-sc));
    __syncthreads();

    // e0[t,u] = sum_s Ve[t,s] * sig[s,u]
    float e = 0.f;
#pragma unroll
    for (int s = 0; s < TT; ++s) {
        e += Ve[t * TT + s] * sig[s][u];
    }
    e0[t][u] = e;
    __syncthreads();

    // softmax over t (dim 1) for each column u
    float m = -1e30f;
#pragma unroll
    for (int tt = 0; tt < TT; ++tt) m = fmaxf(m, e0[tt][u]);
    float mysig = __expf(e - m);
    float sum = 0.f;
#pragma unroll
    for (int tt = 0; tt < TT; ++tt) sum += __expf(e0[tt][u] - m);
    E[((size_t)b * TT + t) * TT + u] = mysig / sum;
}

// ---------------- X_hat[b,n,c,s] = sum_t X[b,n,c,t] * E[b,t,s] ----------------
// one thread per (n,c) row; row's 32 inputs in regs, E is block-uniform (SGPR).
__global__ __launch_bounds__(256) void k_xhat(const float* __restrict__ X,
                                              const float* __restrict__ E,
                                              float* __restrict__ Y) {
    const int blocks_per_b = (NN * CC) / 256;  // 250
    int b = blockIdx.x / blocks_per_b;
    int r = (blockIdx.x % blocks_per_b) * 256 + threadIdx.x;  // n*CC + c within b
    size_t row = (size_t)b * NN * CC + r;
    const float* xp = X + row * TT;
    float x[TT];
#pragma unroll
    for (int j = 0; j < TT / 4; ++j) {
        float4 v = ((const float4*)xp)[j];
        x[4 * j + 0] = v.x; x[4 * j + 1] = v.y;
        x[4 * j + 2] = v.z; x[4 * j + 3] = v.w;
    }
    const float* Eb = E + (size_t)b * TT * TT;
    float acc[TT];
#pragma unroll
    for (int s = 0; s < TT; ++s) acc[s] = 0.f;
#pragma unroll 4
    for (int t = 0; t < TT; ++t) {
        float xt = x[t];
#pragma unroll
        for (int s = 0; s < TT; ++s) {
            acc[s] += xt * Eb[t * TT + s];
        }
    }
    float* yp = Y + row * TT;
#pragma unroll
    for (int j = 0; j < TT / 4; ++j) {
        float4 v = make_float4(acc[4 * j + 0], acc[4 * j + 1],
                               acc[4 * j + 2], acc[4 * j + 3]);
        ((float4*)yp)[j] = v;
    }
}

extern "C" void kernel_launch(void* const* d_in, const int* in_sizes, int n_in,
                              void* d_out, int out_size, void* d_ws, size_t ws_size,
                              hipStream_t stream) {
    const float* X  = (const float*)d_in[0];
    const float* U1 = (const float*)d_in[1];
    const float* U2 = (const float*)d_in[2];
    const float* U3 = (const float*)d_in[3];
    const float* be = (const float*)d_in[4];
    const float* Ve = (const float*)d_in[5];
    float* Y = (float*)d_out;

    // workspace carve (floats): A | rhs | G | E   (~9.5 MB total)
    float* A   = (float*)d_ws;
    float* rhs = A + (size_t)BB * TT * CC;        // 131072
    float* G   = rhs + (size_t)BB * NN * TT;      // +2,048,000
    float* E   = G + (size_t)BB * CC * TT;        // +131072

    k_A<<<BB * (CC / 8), 256, 0, stream>>>(X, U1, A);
    k_rhs<<<(BB * NN * TT) / 256, 256, 0, stream>>>(X, U3, rhs);
    k_G<<<(BB * CC * TT) / 256, 256, 0, stream>>>(rhs, U2, G);
    k_E<<<BB, 1024, 0, stream>>>(A, G, be, Ve, E);
    k_xhat<<<BB * ((NN * CC) / 256), 256, 0, stream>>>(X, E, Y);
}

// Round 2
// 531.164 us; speedup vs baseline: 1.1204x; 1.1204x over previous
//
#include <hip/hip_runtime.h>
#include <math.h>

#define BB 64
#define NN 1000
#define CC 64
#define TT 32
#define NCH 40
#define NCHUNKS 25  // NN / NCH

// ---- Fused pass 1: one read of X produces rhs and chunked A-partials ----
// grid = BB * NCHUNKS blocks, 256 threads = (t = tid&31, nl = tid>>5).
// Each thread: for its 5 n's (n0 + 8i + nl), load x[c]=X[b,n,c,t] for c=0..63,
//   rhs[b,n,t] = sum_c U3[c]*x[c]          (in-thread, written immediately)
//   accA[c]   += U1[n]*x[c]                (64 per-thread accumulators)
// Epilogue: reduce accA over nl (8 partials) via LDS, write Apart[ch][b][t][c].
__global__ __launch_bounds__(256) void k_p1(const float* __restrict__ X,
                                            const float* __restrict__ U1,
                                            const float* __restrict__ U3,
                                            float* __restrict__ rhs,
                                            float* __restrict__ Apart) {
    int b  = blockIdx.x / NCHUNKS;
    int ch = blockIdx.x % NCHUNKS;
    int t  = threadIdx.x & 31;
    int nl = threadIdx.x >> 5;
    int n0 = ch * NCH;

    float accA[CC];
#pragma unroll
    for (int c = 0; c < CC; ++c) accA[c] = 0.f;

    for (int i = 0; i < NCH / 8; ++i) {
        int n = n0 + i * 8 + nl;
        const float* xp = X + ((size_t)(b * NN + n) * CC) * TT + t;
        float u1 = U1[n];
        float r = 0.f;
#pragma unroll
        for (int c = 0; c < CC; ++c) {
            float x = xp[c * TT];
            r += U3[c] * x;
            accA[c] += u1 * x;
        }
        rhs[(size_t)(b * NN + n) * TT + t] = r;
    }

    // reduce accA over nl: 8 strips of 8 c's through padded LDS
    __shared__ float buf[8][32][9];
    int t2 = threadIdx.x & 31;
    int j2 = threadIdx.x >> 5;
    for (int strip = 0; strip < 8; ++strip) {
        __syncthreads();
#pragma unroll
        for (int j = 0; j < 8; ++j) buf[nl][t][j] = accA[strip * 8 + j];
        __syncthreads();
        float v = 0.f;
#pragma unroll
        for (int k = 0; k < 8; ++k) v += buf[k][t2][j2];
        Apart[((size_t)(ch * BB + b) * TT + t2) * CC + strip * 8 + j2] = v;
    }
}

// ---------------- G[b,c,s] = sum_n U2[c,n] * rhs[b,n,s] ----------------
__global__ __launch_bounds__(256) void k_G(const float* __restrict__ rhs,
                                           const float* __restrict__ U2,
                                           float* __restrict__ G) {
    size_t idx = (size_t)blockIdx.x * blockDim.x + threadIdx.x;
    int s = (int)(idx & 31);
    int c = (int)((idx >> 5) & (CC - 1));
    int b = (int)(idx >> 11);
    const float* rp = rhs + (size_t)b * NN * TT + s;
    const float* up = U2 + (size_t)c * NN;
    float acc = 0.f;
#pragma unroll 4
    for (int n = 0; n < NN; ++n) {
        acc += up[n] * rp[(size_t)n * TT];
    }
    G[idx] = acc;
}

// ---- E[b,t,u]: reduce Apart -> scores -> sigmoid -> Ve @ . -> softmax over t ----
// one block per b, 1024 threads = (t = tid>>5, u = tid&31)
__global__ __launch_bounds__(1024) void k_E(const float* __restrict__ Apart,
                                            const float* __restrict__ G,
                                            const float* __restrict__ be,
                                            const float* __restrict__ Ve,
                                            float* __restrict__ E) {
    int b = blockIdx.x;
    int u = threadIdx.x & 31;
    int t = threadIdx.x >> 5;
    __shared__ float As[TT][CC + 1];
    __shared__ float sig[TT][TT];
    __shared__ float e0[TT][TT];

    // deterministic reduction of A chunk-partials: thread (t,u) owns c=u, c=u+32
    float a0 = 0.f, a1 = 0.f;
    for (int ch = 0; ch < NCHUNKS; ++ch) {
        const float* ap = Apart + ((size_t)(ch * BB + b) * TT + t) * CC;
        a0 += ap[u];
        a1 += ap[u + 32];
    }
    As[t][u] = a0;
    As[t][u + 32] = a1;
    __syncthreads();

    const float* Gb = G + (size_t)b * CC * TT;
    float sc = be[t * TT + u];
#pragma unroll
    for (int c = 0; c < CC; ++c) {
        sc += As[t][c] * Gb[c * TT + u];
    }
    sig[t][u] = 1.f / (1.f + __expf(-sc));
    __syncthreads();

    float e = 0.f;
#pragma unroll
    for (int s = 0; s < TT; ++s) {
        e += Ve[t * TT + s] * sig[s][u];
    }
    e0[t][u] = e;
    __syncthreads();

    float m = -1e30f;
#pragma unroll
    for (int tt = 0; tt < TT; ++tt) m = fmaxf(m, e0[tt][u]);
    float mysig = __expf(e - m);
    float sum = 0.f;
#pragma unroll
    for (int tt = 0; tt < TT; ++tt) sum += __expf(e0[tt][u] - m);
    E[((size_t)b * TT + t) * TT + u] = mysig / sum;
}

// ---------------- X_hat[b,n,c,s] = sum_t X[b,n,c,t] * E[b,t,s] ----------------
__global__ __launch_bounds__(256) void k_xhat(const float* __restrict__ X,
                                              const float* __restrict__ E,
                                              float* __restrict__ Y) {
    const int blocks_per_b = (NN * CC) / 256;  // 250
    int b = blockIdx.x / blocks_per_b;
    int r = (blockIdx.x % blocks_per_b) * 256 + threadIdx.x;
    size_t row = (size_t)b * NN * CC + r;
    const float* xp = X + row * TT;
    float x[TT];
#pragma unroll
    for (int j = 0; j < TT / 4; ++j) {
        float4 v = ((const float4*)xp)[j];
        x[4 * j + 0] = v.x; x[4 * j + 1] = v.y;
        x[4 * j + 2] = v.z; x[4 * j + 3] = v.w;
    }
    const float* Eb = E + (size_t)b * TT * TT;
    float acc[TT];
#pragma unroll
    for (int s = 0; s < TT; ++s) acc[s] = 0.f;
#pragma unroll 4
    for (int t = 0; t < TT; ++t) {
        float xt = x[t];
#pragma unroll
        for (int s = 0; s < TT; ++s) {
            acc[s] += xt * Eb[t * TT + s];
        }
    }
    float* yp = Y + row * TT;
#pragma unroll
    for (int j = 0; j < TT / 4; ++j) {
        float4 v = make_float4(acc[4 * j + 0], acc[4 * j + 1],
                               acc[4 * j + 2], acc[4 * j + 3]);
        ((float4*)yp)[j] = v;
    }
}

extern "C" void kernel_launch(void* const* d_in, const int* in_sizes, int n_in,
                              void* d_out, int out_size, void* d_ws, size_t ws_size,
                              hipStream_t stream) {
    const float* X  = (const float*)d_in[0];
    const float* U1 = (const float*)d_in[1];
    const float* U2 = (const float*)d_in[2];
    const float* U3 = (const float*)d_in[3];
    const float* be = (const float*)d_in[4];
    const float* Ve = (const float*)d_in[5];
    float* Y = (float*)d_out;

    // workspace carve (floats): rhs | Apart | G | E   (~22.4 MB total)
    float* rhs   = (float*)d_ws;
    float* Apart = rhs + (size_t)BB * NN * TT;                 // +2,048,000
    float* G     = Apart + (size_t)NCHUNKS * BB * TT * CC;     // +3,276,800
    float* E     = G + (size_t)BB * CC * TT;                   // +131,072

    k_p1<<<BB * NCHUNKS, 256, 0, stream>>>(X, U1, U3, rhs, Apart);
    k_G<<<(BB * CC * TT) / 256, 256, 0, stream>>>(rhs, U2, G);
    k_E<<<BB, 1024, 0, stream>>>(Apart, G, be, Ve, E);
    k_xhat<<<BB * ((NN * CC) / 256), 256, 0, stream>>>(X, E, Y);
}

// Round 4
// 389.690 us; speedup vs baseline: 1.5272x; 1.3630x over previous
//
#include <hip/hip_runtime.h>
#include <math.h>

#define BB 64
#define NN 1000
#define CC 64
#define TT 32
#define NCH 40
#define NCHUNKS 25  // NN / NCH

typedef float floatx4 __attribute__((ext_vector_type(4)));

// ---- Fused pass 1: one read of X produces rhs and chunked A-partials ----
// grid = BB * NCHUNKS blocks, 256 threads = (t = tid&31, nl = tid>>5).
__global__ __launch_bounds__(256) void k_p1(const float* __restrict__ X,
                                            const float* __restrict__ U1,
                                            const float* __restrict__ U3,
                                            float* __restrict__ rhs,
                                            float* __restrict__ Apart) {
    int b  = blockIdx.x / NCHUNKS;
    int ch = blockIdx.x % NCHUNKS;
    int t  = threadIdx.x & 31;
    int nl = threadIdx.x >> 5;
    int n0 = ch * NCH;

    float accA[CC];
#pragma unroll
    for (int c = 0; c < CC; ++c) accA[c] = 0.f;

    for (int i = 0; i < NCH / 8; ++i) {
        int n = n0 + i * 8 + nl;
        const float* xp = X + ((size_t)(b * NN + n) * CC) * TT + t;
        float u1 = U1[n];
        float r = 0.f;
#pragma unroll
        for (int c = 0; c < CC; ++c) {
            float x = __builtin_nontemporal_load(&xp[c * TT]);
            r += U3[c] * x;
            accA[c] += u1 * x;
        }
        rhs[(size_t)(b * NN + n) * TT + t] = r;
    }

    // reduce accA over nl: 8 strips of 8 c's through padded LDS
    __shared__ float buf[8][32][9];
    int t2 = threadIdx.x & 31;
    int j2 = threadIdx.x >> 5;
    for (int strip = 0; strip < 8; ++strip) {
        __syncthreads();
#pragma unroll
        for (int j = 0; j < 8; ++j) buf[nl][t][j] = accA[strip * 8 + j];
        __syncthreads();
        float v = 0.f;
#pragma unroll
        for (int k = 0; k < 8; ++k) v += buf[k][t2][j2];
        Apart[((size_t)(ch * BB + b) * TT + t2) * CC + strip * 8 + j2] = v;
    }
}

// ---------------- G[b,c,s] = sum_n U2[c,n] * rhs[b,n,s] ----------------
__global__ __launch_bounds__(256) void k_G(const float* __restrict__ rhs,
                                           const float* __restrict__ U2,
                                           float* __restrict__ G) {
    size_t idx = (size_t)blockIdx.x * blockDim.x + threadIdx.x;
    int s = (int)(idx & 31);
    int c = (int)((idx >> 5) & (CC - 1));
    int b = (int)(idx >> 11);
    const float* rp = rhs + (size_t)b * NN * TT + s;
    const float* up = U2 + (size_t)c * NN;
    float a0 = 0.f, a1 = 0.f, a2 = 0.f, a3 = 0.f;
#pragma unroll 2
    for (int n = 0; n < NN; n += 4) {
        a0 += up[n + 0] * rp[(size_t)(n + 0) * TT];
        a1 += up[n + 1] * rp[(size_t)(n + 1) * TT];
        a2 += up[n + 2] * rp[(size_t)(n + 2) * TT];
        a3 += up[n + 3] * rp[(size_t)(n + 3) * TT];
    }
    G[idx] = (a0 + a1) + (a2 + a3);
}

// ---- E[b,t,u]: reduce Apart -> scores -> sigmoid -> Ve @ . -> softmax over t ----
__global__ __launch_bounds__(1024) void k_E(const float* __restrict__ Apart,
                                            const float* __restrict__ G,
                                            const float* __restrict__ be,
                                            const float* __restrict__ Ve,
                                            float* __restrict__ E) {
    int b = blockIdx.x;
    int u = threadIdx.x & 31;
    int t = threadIdx.x >> 5;
    __shared__ float As[TT][CC + 1];
    __shared__ float sig[TT][TT];
    __shared__ float e0[TT][TT];

    float a0 = 0.f, a1 = 0.f;
    for (int ch = 0; ch < NCHUNKS; ++ch) {
        const float* ap = Apart + ((size_t)(ch * BB + b) * TT + t) * CC;
        a0 += ap[u];
        a1 += ap[u + 32];
    }
    As[t][u] = a0;
    As[t][u + 32] = a1;
    __syncthreads();

    const float* Gb = G + (size_t)b * CC * TT;
    float sc = be[t * TT + u];
#pragma unroll
    for (int c = 0; c < CC; ++c) {
        sc += As[t][c] * Gb[c * TT + u];
    }
    sig[t][u] = 1.f / (1.f + __expf(-sc));
    __syncthreads();

    float e = 0.f;
#pragma unroll
    for (int s = 0; s < TT; ++s) {
        e += Ve[t * TT + s] * sig[s][u];
    }
    e0[t][u] = e;
    __syncthreads();

    float m = -1e30f;
#pragma unroll
    for (int tt = 0; tt < TT; ++tt) m = fmaxf(m, e0[tt][u]);
    float mysig = __expf(e - m);
    float sum = 0.f;
#pragma unroll
    for (int tt = 0; tt < TT; ++tt) sum += __expf(e0[tt][u] - m);
    E[((size_t)b * TT + t) * TT + u] = mysig / sum;
}

// ---------------- X_hat[b,n,c,s] = sum_t X[b,n,c,t] * E[b,t,s] ----------------
// Per-thread row compute in registers; stores transposed through XOR-swizzled
// LDS so each wave store instruction writes 1 KB contiguous (no partial-line RFO).
__global__ __launch_bounds__(256) void k_xhat(const float* __restrict__ X,
                                              const float* __restrict__ E,
                                              float* __restrict__ Y) {
    const int blocks_per_b = (NN * CC) / 256;  // 250
    int b = blockIdx.x / blocks_per_b;
    int tid = threadIdx.x;
    size_t row = (size_t)blockIdx.x * 256 + tid;  // global (b,n,c) row
    const float* xp = X + row * TT;
    float x[TT];
#pragma unroll
    for (int j = 0; j < TT / 4; ++j) {
        floatx4 v = *(const floatx4*)(xp + 4 * j);
        x[4 * j + 0] = v.x; x[4 * j + 1] = v.y;
        x[4 * j + 2] = v.z; x[4 * j + 3] = v.w;
    }
    const float* Eb = E + (size_t)b * TT * TT;
    float acc[TT];
#pragma unroll
    for (int s = 0; s < TT; ++s) acc[s] = 0.f;
#pragma unroll 4
    for (int t = 0; t < TT; ++t) {
        float xt = x[t];
#pragma unroll
        for (int s = 0; s < TT; ++s) {
            acc[s] += xt * Eb[t * TT + s];
        }
    }

    // transpose through LDS: quad-granularity XOR swizzle, conflict-free
    __shared__ floatx4 ly[256 * 8];  // 32 KB
#pragma unroll
    for (int q = 0; q < 8; ++q) {
        floatx4 v = { acc[4 * q + 0], acc[4 * q + 1],
                      acc[4 * q + 2], acc[4 * q + 3] };
        ly[tid * 8 + (q ^ (tid & 7))] = v;
    }
    __syncthreads();

    floatx4* Yq = (floatx4*)Y;
    size_t qbase = (size_t)blockIdx.x * 2048;
#pragma unroll
    for (int k = 0; k < 8; ++k) {
        int g = k * 256 + tid;
        int lr = g >> 3;
        int q = g & 7;
        floatx4 v = ly[lr * 8 + (q ^ (lr & 7))];
        __builtin_nontemporal_store(v, &Yq[qbase + g]);
    }
}

extern "C" void kernel_launch(void* const* d_in, const int* in_sizes, int n_in,
                              void* d_out, int out_size, void* d_ws, size_t ws_size,
                              hipStream_t stream) {
    const float* X  = (const float*)d_in[0];
    const float* U1 = (const float*)d_in[1];
    const float* U2 = (const float*)d_in[2];
    const float* U3 = (const float*)d_in[3];
    const float* be = (const float*)d_in[4];
    const float* Ve = (const float*)d_in[5];
    float* Y = (float*)d_out;

    // workspace carve (floats): rhs | Apart | G | E
    float* rhs   = (float*)d_ws;
    float* Apart = rhs + (size_t)BB * NN * TT;                 // +2,048,000
    float* G     = Apart + (size_t)NCHUNKS * BB * TT * CC;     // +3,276,800
    float* E     = G + (size_t)BB * CC * TT;                   // +131,072

    k_p1<<<BB * NCHUNKS, 256, 0, stream>>>(X, U1, U3, rhs, Apart);
    k_G<<<(BB * CC * TT) / 256, 256, 0, stream>>>(rhs, U2, G);
    k_E<<<BB, 1024, 0, stream>>>(Apart, G, be, Ve, E);
    k_xhat<<<BB * ((NN * CC) / 256), 256, 0, stream>>>(X, E, Y);
}